// Round 15
// baseline (903.253 us; speedup 1.0000x reference)
//
#include <hip/hip_runtime.h>
#include <math.h>

constexpr int Bn = 8;
constexpr int Np = 2048;
constexpr int Kn = 32;
constexpr float NEGS = 0.2f;

typedef __attribute__((ext_vector_type(8))) short short8;
typedef __attribute__((ext_vector_type(4))) float f32x4;
typedef unsigned short ushortT;

__device__ __forceinline__ float lrelu(float v) { return v > 0.f ? v : NEGS * v; }

// DPP-based max step; ctrl/rmask as template args (builtin requires ICE operands)
template<int CTRL, int RMASK>
__device__ __forceinline__ float dppmax(float v) {
    int o = __float_as_int(v);
    int s = __builtin_amdgcn_update_dpp(o, o, CTRL, RMASK, 0xf, false);
    return fmaxf(v, __int_as_float(s));
}
// full 64-lane max via DPP (valid in lane 63), then readlane-broadcast
__device__ __forceinline__ float wave_max_dpp(float v) {
    v = dppmax<0x111, 0xf>(v);   // row_shr:1
    v = dppmax<0x112, 0xf>(v);   // row_shr:2
    v = dppmax<0x114, 0xf>(v);   // row_shr:4
    v = dppmax<0x118, 0xf>(v);   // row_shr:8
    v = dppmax<0x142, 0xa>(v);   // row_bcast:15 -> rows 1,3
    v = dppmax<0x143, 0xc>(v);   // row_bcast:31 -> row 3
    return __int_as_float(__builtin_amdgcn_readlane(__float_as_int(v), 63));
}

// split fp32 -> bf16 hi (truncate) + bf16 lo (residual, truncate); packed 2-at-a-time
__device__ __forceinline__ void cvt2u(float a, float b, unsigned& h, unsigned& l) {
    unsigned ua = __float_as_uint(a), ub = __float_as_uint(b);
    h = (ua >> 16) | (ub & 0xffff0000u);
    float ra = a - __uint_as_float(ua & 0xffff0000u);
    float rb = b - __uint_as_float(ub & 0xffff0000u);
    l = (__float_as_uint(ra) >> 16) | (__float_as_uint(rb) & 0xffff0000u);
}

// x [B,3,N] -> pts point-major [B*N, 4] (pad lane = 0)
__global__ __launch_bounds__(256) void k_transpose(const float* __restrict__ x, float* __restrict__ pts) {
    int i = blockIdx.x * 256 + threadIdx.x;
    int b = i / Np, n = i % Np;
    float p0 = x[((size_t)b * 3 + 0) * Np + n];
    float p1 = x[((size_t)b * 3 + 1) * Np + n];
    float p2 = x[((size_t)b * 3 + 2) * Np + n];
    float4 v = make_float4(p0, p1, p2, 0.f);
    *(float4*)&pts[(size_t)i * 4] = v;
}

// xx[i] = sum_c pm[i*ld+c]^2 ; one wave per point, 4 points per block
__global__ __launch_bounds__(256) void k_xx(const float* __restrict__ pm, float* __restrict__ xxg, int C, int ld) {
    int wid = threadIdx.x >> 6, lane = threadIdx.x & 63;
    int pt = blockIdx.x * 4 + wid;
    const float* row = pm + (size_t)pt * ld;
    float acc = 0.f;
    for (int c = lane; c < C; c += 64) { float v = row[c]; acc = fmaf(v, v, acc); }
    #pragma unroll
    for (int off = 32; off; off >>= 1) acc += __shfl_down(acc, off, 64);
    if (lane == 0) xxg[pt] = acc;
}

// Pack points into mfma_16x16x32 B-fragment order (bf16 hi/lo), per batch.
template<int C, int CK, int LD>
__global__ __launch_bounds__(256) void k_bpack(const float* __restrict__ Xpm,
                                               ushortT* __restrict__ Bh, ushortT* __restrict__ Bl) {
    constexpr int KS = CK / 32;
    int i = blockIdx.x * 256 + threadIdx.x;
    int j = i & 7;
    int lane = (i >> 3) & 63;
    int nt = (i >> 9) & 127;
    int rest = i >> 16;
    int ks = rest % KS;
    int b = rest / KS;
    int k = ks * 32 + (lane >> 4) * 8 + j;
    int n = nt * 16 + (lane & 15);
    float v = (k < C) ? Xpm[((size_t)b * Np + n) * LD + k] : 0.f;
    unsigned u = __float_as_uint(v);
    Bh[i] = (ushortT)(u >> 16);
    float r = v - __uint_as_float(u & 0xffff0000u);
    Bl[i] = (ushortT)(__float_as_uint(r) >> 16);
}

// MFMA kNN v8: 512 threads / 8 waves; MFMA phase chunked as v7; selection gives each
// wave TWO rows (2w, 2w+1) with interleaved independent extraction chains to hide the
// DPP/ballot latency. Per-row algorithm identical to v7.
template<int C, int CK, int LD>
__global__ __launch_bounds__(512) void k_knn6(const float* __restrict__ Xpm,
                                              const ushortT* __restrict__ Bh, const ushortT* __restrict__ Bl,
                                              const float* __restrict__ xxg, int* __restrict__ idxo) {
    constexpr int KS = CK / 32, CP = CK + 8, CK4 = CK / 4, C4src = LD / 4;
    constexpr int SD = 1026;
    extern __shared__ char smem[];
    ushortT* Ah = (ushortT*)smem;              // [16][CP]
    ushortT* Al = Ah + 16 * CP;                // [16][CP]
    float* xxm = (float*)(Al + 16 * CP);       // [16]
    float* dl = xxm + 16;                      // [16][SD] distances (one column-half)
    int b = blockIdx.x / (Np / 16);
    int n0 = (blockIdx.x % (Np / 16)) * 16;
    int t = threadIdx.x;
    const float4* Xp4 = (const float4*)Xpm;
    for (int e = t; e < 16 * CK4; e += 512) {
        int r = e / CK4, c4 = e % CK4;
        float4 v = (c4 < C4src) ? Xp4[((size_t)b * Np + n0 + r) * C4src + c4] : make_float4(0.f, 0.f, 0.f, 0.f);
        unsigned h0, l0, h1, l1;
        cvt2u(v.x, v.y, h0, l0);
        cvt2u(v.z, v.w, h1, l1);
        *(uint2*)&Ah[r * CP + 4 * c4] = make_uint2(h0, h1);
        *(uint2*)&Al[r * CP + 4 * c4] = make_uint2(l0, l1);
    }
    if (t < 16) xxm[t] = xxg[b * Np + t + n0];
    __syncthreads();

    int w = t >> 6, lane = t & 63;
    int quad = lane >> 4, col = lane & 15;
    short8 ah[KS], al[KS];
    #pragma unroll
    for (int ks = 0; ks < KS; ++ks) {
        ah[ks] = *(const short8*)&Ah[col * CP + ks * 32 + quad * 8];
        al[ks] = *(const short8*)&Al[col * CP + ks * 32 + quad * 8];
    }
    float xmr[4];
    #pragma unroll
    for (int r = 0; r < 4; ++r) xmr[r] = xxm[quad * 4 + r];

    float v0[32], v1[32];
    #pragma unroll
    for (int cc = 0; cc < 2; ++cc) {
        // MFMA: 8 n-tiles per wave per chunk (2 at a time); chunk covers 64 tiles
        for (int i = 0; i < 4; ++i) {
            int ntl0 = w * 8 + 2 * i, ntl1 = ntl0 + 1;
            int ng0 = cc * 64 + ntl0, ng1 = cc * 64 + ntl1;
            f32x4 a0 = (f32x4){0.f, 0.f, 0.f, 0.f};
            f32x4 a1 = (f32x4){0.f, 0.f, 0.f, 0.f};
            #pragma unroll
            for (int ks = 0; ks < KS; ++ks) {
                int bi0 = (((b * KS + ks) * 128 + ng0) * 64 + lane) * 8;
                int bi1 = (((b * KS + ks) * 128 + ng1) * 64 + lane) * 8;
                short8 bh0 = *(const short8*)(Bh + bi0);
                short8 bl0 = *(const short8*)(Bl + bi0);
                short8 bh1 = *(const short8*)(Bh + bi1);
                short8 bl1 = *(const short8*)(Bl + bi1);
                a0 = __builtin_amdgcn_mfma_f32_16x16x32_bf16(ah[ks], bh0, a0, 0, 0, 0);
                a1 = __builtin_amdgcn_mfma_f32_16x16x32_bf16(ah[ks], bh1, a1, 0, 0, 0);
                a0 = __builtin_amdgcn_mfma_f32_16x16x32_bf16(ah[ks], bl0, a0, 0, 0, 0);
                a1 = __builtin_amdgcn_mfma_f32_16x16x32_bf16(ah[ks], bl1, a1, 0, 0, 0);
                a0 = __builtin_amdgcn_mfma_f32_16x16x32_bf16(al[ks], bh0, a0, 0, 0, 0);
                a1 = __builtin_amdgcn_mfma_f32_16x16x32_bf16(al[ks], bh1, a1, 0, 0, 0);
            }
            float xn0 = xxg[b * Np + ng0 * 16 + col];
            float xn1 = xxg[b * Np + ng1 * 16 + col];
            #pragma unroll
            for (int r = 0; r < 4; ++r) {
                int m = quad * 4 + r;
                dl[m * SD + ntl0 * 16 + col] = 2.f * a0[r] - xmr[r] - xn0;
                dl[m * SD + ntl1 * 16 + col] = 2.f * a1[r] - xmr[r] - xn1;
            }
        }
        __syncthreads();
        const float* dr0 = dl + (2 * w) * SD;
        const float* dr1 = dl + (2 * w + 1) * SD;
        #pragma unroll
        for (int j = 0; j < 16; ++j) {
            v0[cc * 16 + j] = dr0[lane + 64 * j];
            v1[cc * 16 + j] = dr1[lane + 64 * j];
        }
        __syncthreads();
    }

    // ---- selection: wave w owns rows 2w, 2w+1; two interleaved exact chains ----
    float g00, g01, g02, g03, g10, g11, g12, g13;
    int j00, j01, j02, j03, j10, j11, j12, j13;
    g00 = v0[0]; j00 = 0;
    g10 = v1[0]; j10 = 0;
    #pragma unroll
    for (int e = 1; e < 8; ++e) {
        if (v0[e] > g00) { g00 = v0[e]; j00 = e; }
        if (v1[e] > g10) { g10 = v1[e]; j10 = e; }
    }
    g01 = v0[8]; j01 = 8;
    g11 = v1[8]; j11 = 8;
    #pragma unroll
    for (int e = 1; e < 8; ++e) {
        if (v0[8 + e] > g01) { g01 = v0[8 + e]; j01 = 8 + e; }
        if (v1[8 + e] > g11) { g11 = v1[8 + e]; j11 = 8 + e; }
    }
    g02 = v0[16]; j02 = 16;
    g12 = v1[16]; j12 = 16;
    #pragma unroll
    for (int e = 1; e < 8; ++e) {
        if (v0[16 + e] > g02) { g02 = v0[16 + e]; j02 = 16 + e; }
        if (v1[16 + e] > g12) { g12 = v1[16 + e]; j12 = 16 + e; }
    }
    g03 = v0[24]; j03 = 24;
    g13 = v1[24]; j13 = 24;
    #pragma unroll
    for (int e = 1; e < 8; ++e) {
        if (v0[24 + e] > g03) { g03 = v0[24 + e]; j03 = 24 + e; }
        if (v1[24 + e] > g13) { g13 = v1[24 + e]; j13 = 24 + e; }
    }

    size_t ob0 = ((size_t)b * Np + n0 + 2 * w) * Kn;
    size_t ob1 = ((size_t)b * Np + n0 + 2 * w + 1) * Kn;
    for (int it = 0; it < Kn; ++it) {
        float lv0 = fmaxf(fmaxf(g00, g01), fmaxf(g02, g03));
        float lv1 = fmaxf(fmaxf(g10, g11), fmaxf(g12, g13));
        float Wv0 = wave_max_dpp(lv0);
        float Wv1 = wave_max_dpp(lv1);
        unsigned long long mk0 = __ballot(lv0 == Wv0);
        unsigned long long mk1 = __ballot(lv1 == Wv1);
        int own0 = __ffsll(mk0) - 1;
        int own1 = __ffsll(mk1) - 1;
        if (lane == own0) {
            int lj;
            if (g00 == Wv0) lj = j00;
            else if (g01 == Wv0) lj = j01;
            else if (g02 == Wv0) lj = j02;
            else lj = j03;
            idxo[ob0 + it] = lane + 64 * lj;
            int gg = lj >> 3;
            if (gg == 0) {
                #pragma unroll
                for (int e = 0; e < 8; ++e) if (e == lj) v0[e] = -INFINITY;
                g00 = v0[0]; j00 = 0;
                #pragma unroll
                for (int e = 1; e < 8; ++e) if (v0[e] > g00) { g00 = v0[e]; j00 = e; }
            } else if (gg == 1) {
                #pragma unroll
                for (int e = 0; e < 8; ++e) if (8 + e == lj) v0[8 + e] = -INFINITY;
                g01 = v0[8]; j01 = 8;
                #pragma unroll
                for (int e = 1; e < 8; ++e) if (v0[8 + e] > g01) { g01 = v0[8 + e]; j01 = 8 + e; }
            } else if (gg == 2) {
                #pragma unroll
                for (int e = 0; e < 8; ++e) if (16 + e == lj) v0[16 + e] = -INFINITY;
                g02 = v0[16]; j02 = 16;
                #pragma unroll
                for (int e = 1; e < 8; ++e) if (v0[16 + e] > g02) { g02 = v0[16 + e]; j02 = 16 + e; }
            } else {
                #pragma unroll
                for (int e = 0; e < 8; ++e) if (24 + e == lj) v0[24 + e] = -INFINITY;
                g03 = v0[24]; j03 = 24;
                #pragma unroll
                for (int e = 1; e < 8; ++e) if (v0[24 + e] > g03) { g03 = v0[24 + e]; j03 = 24 + e; }
            }
        }
        if (lane == own1) {
            int lj;
            if (g10 == Wv1) lj = j10;
            else if (g11 == Wv1) lj = j11;
            else if (g12 == Wv1) lj = j12;
            else lj = j13;
            idxo[ob1 + it] = lane + 64 * lj;
            int gg = lj >> 3;
            if (gg == 0) {
                #pragma unroll
                for (int e = 0; e < 8; ++e) if (e == lj) v1[e] = -INFINITY;
                g10 = v1[0]; j10 = 0;
                #pragma unroll
                for (int e = 1; e < 8; ++e) if (v1[e] > g10) { g10 = v1[e]; j10 = e; }
            } else if (gg == 1) {
                #pragma unroll
                for (int e = 0; e < 8; ++e) if (8 + e == lj) v1[8 + e] = -INFINITY;
                g11 = v1[8]; j11 = 8;
                #pragma unroll
                for (int e = 1; e < 8; ++e) if (v1[8 + e] > g11) { g11 = v1[8 + e]; j11 = 8 + e; }
            } else if (gg == 2) {
                #pragma unroll
                for (int e = 0; e < 8; ++e) if (16 + e == lj) v1[16 + e] = -INFINITY;
                g12 = v1[16]; j12 = 16;
                #pragma unroll
                for (int e = 1; e < 8; ++e) if (v1[16 + e] > g12) { g12 = v1[16 + e]; j12 = 16 + e; }
            } else {
                #pragma unroll
                for (int e = 0; e < 8; ++e) if (24 + e == lj) v1[24 + e] = -INFINITY;
                g13 = v1[24]; j13 = 24;
                #pragma unroll
                for (int e = 1; e < 8; ++e) if (v1[24 + e] > g13) { g13 = v1[24 + e]; j13 = 24 + e; }
            }
        }
    }
}

// W split+scale+transpose (fp32, for k_ctr): WdsT[c][o] = (W[o][C+c]-W[o][c])*s[o]
__global__ __launch_bounds__(256) void k_wsplit(const float* __restrict__ W, const float* __restrict__ s,
                                                int C, int O, float* __restrict__ WnsT, float* __restrict__ WdsT) {
    int i = blockIdx.x * 256 + threadIdx.x;
    if (i >= C * O) return;
    int c = i / O, o = i % O;
    float a = W[(size_t)o * 2 * C + c];
    float q = W[(size_t)o * 2 * C + C + c];
    float sv = s[o];
    WnsT[i] = a * sv;
    WdsT[i] = (q - a) * sv;
}

// Pack neighbor-half of W (scaled) into mfma_16x16x32 B-fragment order, split bf16 hi/lo.
__global__ __launch_bounds__(256) void k_wpack(const float* __restrict__ W, const float* __restrict__ s,
                                               int C, int O, ushortT* __restrict__ Bh, ushortT* __restrict__ Bl) {
    int i = blockIdx.x * 256 + threadIdx.x;
    if (i >= C * O) return;
    int k = i / O, o = i % O;
    float v = W[(size_t)o * 2 * C + k] * s[o];
    int ks = k >> 5, quad = (k >> 3) & 3, j = k & 7;
    int nt = o >> 4, lane = quad * 16 + (o & 15);
    int NT = O / 16;
    size_t idx = (((size_t)(ks * NT + nt)) * 64 + lane) * 8 + j;
    unsigned u = __float_as_uint(v);
    Bh[idx] = (ushortT)(u >> 16);
    float r = v - __uint_as_float(u & 0xffff0000u);
    Bl[idx] = (ushortT)(__float_as_uint(r) >> 16);
}

// Pack W5 (scaled by s5) [1024][512] into fragment order: KS=16, NT=64.
__global__ __launch_bounds__(256) void k_w5pack(const float* __restrict__ W5, const float* __restrict__ s5,
                                                ushortT* __restrict__ Bh, ushortT* __restrict__ Bl) {
    int i = blockIdx.x * 256 + threadIdx.x;   // 512*1024
    int k = i >> 10, o = i & 1023;
    float v = W5[(size_t)o * 512 + k] * s5[o];
    int ks = k >> 5, quad = (k >> 3) & 3, j = k & 7;
    int nt = o >> 4, lane = quad * 16 + (o & 15);
    size_t idx = (((size_t)(ks * 64 + nt)) * 64 + lane) * 8 + j;
    unsigned u = __float_as_uint(v);
    Bh[idx] = (ushortT)(u >> 16);
    float r = v - __uint_as_float(u & 0xffff0000u);
    Bl[idx] = (ushortT)(__float_as_uint(r) >> 16);
}

// cb[n][o] = sum_c ctr[n][c]*WdsT[c][o] + b[o].  32 points per block.
template<int C, int O, int OPT>
__global__ __launch_bounds__(256) void k_ctr(const float* __restrict__ Xpm, const float* __restrict__ WdsT,
                                             const float* __restrict__ bg, float* __restrict__ cb) {
    constexpr int OG = O / OPT, MG = 256 / OG, MPT = 32 / MG;
    constexpr int C4 = C / 4;
    __shared__ float xs[32][C];
    int b = blockIdx.x / (Np / 32);
    int n0 = (blockIdx.x % (Np / 32)) * 32;
    int t = threadIdx.x;
    const float4* Xp4 = (const float4*)Xpm;
    for (int e = t; e < 32 * C4; e += 256) {
        int pt = e / C4, c4 = e % C4;
        *(float4*)&xs[pt][4 * c4] = Xp4[((size_t)b * Np + n0 + pt) * C4 + c4];
    }
    __syncthreads();
    int og = t % OG, mg = t / OG;
    int o0 = og * OPT;
    float acc[MPT][OPT] = {};
    for (int c = 0; c < C; ++c) {
        float wv[OPT];
        #pragma unroll
        for (int p4 = 0; p4 < OPT / 4; ++p4)
            *(float4*)&wv[4 * p4] = *(const float4*)&WdsT[(size_t)c * O + o0 + 4 * p4];
        #pragma unroll
        for (int m = 0; m < MPT; ++m) {
            float xv = xs[mg * MPT + m][c];
            #pragma unroll
            for (int p = 0; p < OPT; ++p) acc[m][p] = fmaf(wv[p], xv, acc[m][p]);
        }
    }
    #pragma unroll
    for (int m = 0; m < MPT; ++m) {
        #pragma unroll
        for (int p = 0; p < OPT; ++p) {
            int o = o0 + p;
            cb[((size_t)b * Np + n0 + mg * MPT + m) * O + o] = acc[m][p] + bg[o];
        }
    }
}

// MFMA EdgeConv GEMM v2 (split-bf16): waves split the O dimension.
template<int C, int O, int PTS>
__global__ __launch_bounds__(256, 4) void k_ec3(const float* __restrict__ Xpm, const int* __restrict__ idxg,
                                                const ushortT* __restrict__ Bh, const ushortT* __restrict__ Bl,
                                                const float* __restrict__ cb,
                                                float* __restrict__ Ypm) {
    static_assert(PTS == 2, "M=64 mapping");
    constexpr int M = 64, NT = O / 16, NT4 = NT / 4, KS = C / 32, C4 = C / 4, CP = C + 8;
    static_assert(NT4 >= 1, "O>=64");
    __shared__ ushortT Ah[M][CP];
    __shared__ ushortT Al[M][CP];
    int b = blockIdx.x / (Np / PTS);
    int n0 = (blockIdx.x % (Np / PTS)) * PTS;
    int t = threadIdx.x;
    const int* ip = idxg + ((size_t)b * Np + n0) * Kn;
    const float4* Xp4 = (const float4*)Xpm;
    for (int e = t; e < M * C4; e += 256) {
        int row = e / C4, c4 = e % C4;
        float4 v = Xp4[((size_t)b * Np + ip[row]) * C4 + c4];
        unsigned h0, l0, h1, l1;
        cvt2u(v.x, v.y, h0, l0);
        cvt2u(v.z, v.w, h1, l1);
        *(uint2*)&Ah[row][4 * c4] = make_uint2(h0, h1);
        *(uint2*)&Al[row][4 * c4] = make_uint2(l0, l1);
    }
    __syncthreads();
    int w = t >> 6, lane = t & 63;
    int quad = lane >> 4, col = lane & 15;
    f32x4 acc[4][NT4];
    #pragma unroll
    for (int mt = 0; mt < 4; ++mt)
        #pragma unroll
        for (int i = 0; i < NT4; ++i) acc[mt][i] = (f32x4){0.f, 0.f, 0.f, 0.f};
    for (int ks = 0; ks < KS; ++ks) {
        int kb = ks * 32 + quad * 8;
        short8 ah[4], al[4];
        #pragma unroll
        for (int mt = 0; mt < 4; ++mt) {
            ah[mt] = *(const short8*)&Ah[mt * 16 + col][kb];
            al[mt] = *(const short8*)&Al[mt * 16 + col][kb];
        }
        #pragma unroll
        for (int i = 0; i < NT4; ++i) {
            int nt = w * NT4 + i;
            size_t bi = (((size_t)(ks * NT + nt)) * 64 + lane) * 8;
            short8 bh = *(const short8*)(Bh + bi);
            short8 bl = *(const short8*)(Bl + bi);
            #pragma unroll
            for (int mt = 0; mt < 4; ++mt) {
                acc[mt][i] = __builtin_amdgcn_mfma_f32_16x16x32_bf16(ah[mt], bh, acc[mt][i], 0, 0, 0);
                acc[mt][i] = __builtin_amdgcn_mfma_f32_16x16x32_bf16(ah[mt], bl, acc[mt][i], 0, 0, 0);
                acc[mt][i] = __builtin_amdgcn_mfma_f32_16x16x32_bf16(al[mt], bh, acc[mt][i], 0, 0, 0);
            }
        }
    }
    #pragma unroll
    for (int pt = 0; pt < PTS; ++pt) {
        size_t ni = (size_t)b * Np + n0 + pt;
        #pragma unroll
        for (int i = 0; i < NT4; ++i) {
            f32x4 a0 = acc[2 * pt][i], a1 = acc[2 * pt + 1][i];
            float m = fmaxf(fmaxf(fmaxf(a0[0], a0[1]), fmaxf(a0[2], a0[3])),
                            fmaxf(fmaxf(a1[0], a1[1]), fmaxf(a1[2], a1[3])));
            m = fmaxf(m, __shfl_xor(m, 16, 64));
            m = fmaxf(m, __shfl_xor(m, 32, 64));
            if (lane < 16) {
                int o = (w * NT4 + i) * 16 + col;
                Ypm[ni * O + o] = lrelu(m + cb[ni * O + o]);
            }
        }
    }
}

// Legacy fused EdgeConv for layer 1 (C=3)
template<int C, int CPAD, int O, int OPT, int KPT, int PTS>
__global__ __launch_bounds__(256) void k_edgeconv(
    const float* __restrict__ Xpm, const int* __restrict__ idxg,
    const float* __restrict__ W, const float* __restrict__ sg, const float* __restrict__ bg,
    float* __restrict__ Ypm)
{
    constexpr int OG = O / OPT;
    constexpr int NKG = 256 / OG;
    constexpr int CL = CPAD + 4;
    static_assert(NKG * KPT == Kn, "k mapping");
    __shared__ float nbr[PTS][Kn][CL];
    __shared__ float ctr[PTS][CPAD];
    __shared__ float red[PTS][OPT][4][OG];
    int blk = blockIdx.x;
    int b = blk / (Np / PTS);
    int n0 = (blk % (Np / PTS)) * PTS;
    int t = threadIdx.x;
    int lane = t & 63, wid = t >> 6;
    const int* ip = idxg + ((size_t)b * Np + n0) * Kn;
    const float4* Xp4 = (const float4*)Xpm;
    constexpr int C4 = CPAD / 4;
    for (int e = t; e < PTS * C4; e += 256) {
        int pt = e / C4, c4 = e % C4;
        *(float4*)&ctr[pt][4 * c4] = Xp4[((size_t)b * Np + n0 + pt) * C4 + c4];
    }
    for (int e = t; e < PTS * Kn * C4; e += 256) {
        int pt = e / (Kn * C4);
        int r = e % (Kn * C4);
        int k = r / C4, c4 = r % C4;
        int nb = ip[pt * Kn + k];
        *(float4*)&nbr[pt][k][4 * c4] = Xp4[((size_t)b * Np + nb) * C4 + c4];
    }
    __syncthreads();
    int og = t % OG, kg = t / OG;
    float acc[PTS][OPT][KPT] = {};
    float ctt[PTS][OPT] = {};
    for (int c0 = 0; c0 < CPAD; c0 += 4) {
        float wn[OPT][4], wd[OPT][4];
        #pragma unroll
        for (int p = 0; p < OPT; ++p) {
            #pragma unroll
            for (int cc = 0; cc < 4; ++cc) {
                int c = c0 + cc;
                float a = (c < C) ? W[(size_t)(og + p * OG) * (2 * C) + c] : 0.f;
                float q = (c < C) ? W[(size_t)(og + p * OG) * (2 * C) + C + c] : 0.f;
                wn[p][cc] = a; wd[p][cc] = q - a;
            }
        }
        #pragma unroll
        for (int pt = 0; pt < PTS; ++pt) {
            float4 cv = *(const float4*)&ctr[pt][c0];
            #pragma unroll
            for (int p = 0; p < OPT; ++p) {
                ctt[pt][p] = fmaf(wd[p][0], cv.x, ctt[pt][p]);
                ctt[pt][p] = fmaf(wd[p][1], cv.y, ctt[pt][p]);
                ctt[pt][p] = fmaf(wd[p][2], cv.z, ctt[pt][p]);
                ctt[pt][p] = fmaf(wd[p][3], cv.w, ctt[pt][p]);
            }
        }
        #pragma unroll
        for (int pt = 0; pt < PTS; ++pt) {
            #pragma unroll
            for (int k = 0; k < KPT; ++k) {
                float4 nv = *(const float4*)&nbr[pt][kg * KPT + k][c0];
                #pragma unroll
                for (int p = 0; p < OPT; ++p) {
                    acc[pt][p][k] = fmaf(wn[p][0], nv.x, acc[pt][p][k]);
                    acc[pt][p][k] = fmaf(wn[p][1], nv.y, acc[pt][p][k]);
                    acc[pt][p][k] = fmaf(wn[p][2], nv.z, acc[pt][p][k]);
                    acc[pt][p][k] = fmaf(wn[p][3], nv.w, acc[pt][p][k]);
                }
            }
        }
    }
    #pragma unroll
    for (int pt = 0; pt < PTS; ++pt) {
        #pragma unroll
        for (int p = 0; p < OPT; ++p) {
            int o = og + p * OG;
            float sv = sg[o], bv = bg[o];
            float m = -INFINITY;
            #pragma unroll
            for (int k = 0; k < KPT; ++k) {
                float hv = fmaf(acc[pt][p][k] + ctt[pt][p], sv, bv);
                m = fmaxf(m, lrelu(hv));
            }
            #pragma unroll
            for (int s = OG; s < 64; s <<= 1) m = fmaxf(m, __shfl_xor(m, s, 64));
            if (lane < OG) red[pt][p][wid][lane] = m;
        }
    }
    __syncthreads();
    if (t < OG) {
        #pragma unroll
        for (int pt = 0; pt < PTS; ++pt) {
            #pragma unroll
            for (int p = 0; p < OPT; ++p) {
                float m = fmaxf(fmaxf(red[pt][p][0][t], red[pt][p][1][t]),
                                fmaxf(red[pt][p][2][t], red[pt][p][3][t]));
                int o = t + p * OG;
                Ypm[((size_t)b * Np + n0 + pt) * O + o] = m;
            }
        }
    }
}

// MFMA W5 (K=512, O=1024) + bias + LeakyReLU + max/sum pool over 32 points -> partials.
__global__ __launch_bounds__(1024, 4) void k_w5mfma(
    const float* __restrict__ x1, const float* __restrict__ x2,
    const float* __restrict__ x3, const float* __restrict__ x4,
    const ushortT* __restrict__ Bh, const ushortT* __restrict__ Bl,
    const float* __restrict__ b5,
    float* __restrict__ pmax, float* __restrict__ psum)
{
    constexpr int CP = 520;                 // 512 + 8 pad
    extern __shared__ char smem[];
    ushortT* Ah = (ushortT*)smem;           // [32][CP]
    ushortT* Al = Ah + 32 * CP;             // [32][CP]
    int b = blockIdx.x >> 6;
    int chunk = blockIdx.x & 63;
    int n0 = chunk * 32;
    int t = threadIdx.x;
    for (int e = t; e < 32 * 128; e += 1024) {
        int pt = e >> 7, c4 = e & 127;
        size_t pi = (size_t)b * Np + n0 + pt;
        float4 v;
        if (c4 < 16)      v = ((const float4*)x1)[pi * 16 + c4];
        else if (c4 < 32) v = ((const float4*)x2)[pi * 16 + (c4 - 16)];
        else if (c4 < 64) v = ((const float4*)x3)[pi * 32 + (c4 - 32)];
        else              v = ((const float4*)x4)[pi * 64 + (c4 - 64)];
        unsigned h0, l0, h1, l1;
        cvt2u(v.x, v.y, h0, l0);
        cvt2u(v.z, v.w, h1, l1);
        *(uint2*)&Ah[pt * CP + 4 * c4] = make_uint2(h0, h1);
        *(uint2*)&Al[pt * CP + 4 * c4] = make_uint2(l0, l1);
    }
    __syncthreads();
    int w = t >> 6, lane = t & 63;
    int quad = lane >> 4, col = lane & 15;
    size_t pb = ((size_t)(b * 64 + chunk)) * 1024;
    for (int oi = 0; oi < 4; ++oi) {
        int nt = w * 4 + oi;
        f32x4 a0 = (f32x4){0.f, 0.f, 0.f, 0.f};
        f32x4 a1 = (f32x4){0.f, 0.f, 0.f, 0.f};
        #pragma unroll 2
        for (int ks = 0; ks < 16; ++ks) {
            size_t bi = (((size_t)(ks * 64 + nt)) * 64 + lane) * 8;
            short8 bh = *(const short8*)(Bh + bi);
            short8 bl = *(const short8*)(Bl + bi);
            int ao = ks * 32 + quad * 8;
            short8 ah0 = *(const short8*)&Ah[col * CP + ao];
            short8 al0 = *(const short8*)&Al[col * CP + ao];
            short8 ah1 = *(const short8*)&Ah[(16 + col) * CP + ao];
            short8 al1 = *(const short8*)&Al[(16 + col) * CP + ao];
            a0 = __builtin_amdgcn_mfma_f32_16x16x32_bf16(ah0, bh, a0, 0, 0, 0);
            a1 = __builtin_amdgcn_mfma_f32_16x16x32_bf16(ah1, bh, a1, 0, 0, 0);
            a0 = __builtin_amdgcn_mfma_f32_16x16x32_bf16(ah0, bl, a0, 0, 0, 0);
            a1 = __builtin_amdgcn_mfma_f32_16x16x32_bf16(ah1, bl, a1, 0, 0, 0);
            a0 = __builtin_amdgcn_mfma_f32_16x16x32_bf16(al0, bh, a0, 0, 0, 0);
            a1 = __builtin_amdgcn_mfma_f32_16x16x32_bf16(al1, bh, a1, 0, 0, 0);
        }
        float bb = b5[nt * 16 + col];
        float mx = -INFINITY, sm = 0.f;
        #pragma unroll
        for (int r = 0; r < 4; ++r) {
            float v0 = lrelu(a0[r] + bb);
            float v1 = lrelu(a1[r] + bb);
            mx = fmaxf(mx, fmaxf(v0, v1));
            sm += v0 + v1;
        }
        mx = fmaxf(mx, __shfl_xor(mx, 16, 64));
        mx = fmaxf(mx, __shfl_xor(mx, 32, 64));
        sm += __shfl_xor(sm, 16, 64);
        sm += __shfl_xor(sm, 32, 64);
        if (lane < 16) {
            pmax[pb + nt * 16 + col] = mx;
            psum[pb + nt * 16 + col] = sm;
        }
    }
}

__global__ __launch_bounds__(256) void k_poolred(const float* __restrict__ pmax, const float* __restrict__ psum,
                                                 float* __restrict__ g0) {
    int i = blockIdx.x * 256 + threadIdx.x;
    int b = i >> 10, o = i & 1023;
    float mx = -INFINITY, sm = 0.f;
    for (int ch = 0; ch < 64; ++ch) {
        size_t idx = ((size_t)(b * 64 + ch)) * 1024 + o;
        mx = fmaxf(mx, pmax[idx]);
        sm += psum[idx];
    }
    g0[(size_t)b * 2048 + o] = mx;
    g0[(size_t)b * 2048 + 1024 + o] = sm * (1.f / Np);
}

__global__ __launch_bounds__(256) void k_fc(const float* __restrict__ In, int ldIn, int C,
                                            const float* __restrict__ Wm,
                                            const float* __restrict__ bias,
                                            const float* __restrict__ sc, const float* __restrict__ bnb,
                                            int leaky, float* __restrict__ Out, int ldOut, int O) {
    int wid = threadIdx.x >> 6, lane = threadIdx.x & 63;
    int o = blockIdx.x * 4 + wid;
    int b = blockIdx.y;
    if (o >= O) return;
    const float* in = In + (size_t)b * ldIn;
    const float* wr = Wm + (size_t)o * C;
    float acc = 0.f;
    for (int c = lane; c < C; c += 64) acc = fmaf(in[c], wr[c], acc);
    #pragma unroll
    for (int off = 32; off; off >>= 1) acc += __shfl_down(acc, off, 64);
    if (lane == 0) {
        float v = acc + (bias ? bias[o] : 0.f);
        if (sc) v = fmaf(v, sc[o], bnb[o]);
        if (leaky) v = lrelu(v);
        Out[(size_t)b * ldOut + o] = v;
    }
}

extern "C" void kernel_launch(void* const* d_in, const int* in_sizes, int n_in,
                              void* d_out, int out_size, void* d_ws, size_t ws_size,
                              hipStream_t stream) {
    const float* x   = (const float*)d_in[0];
    const float* W1  = (const float*)d_in[1];
    const float* s1  = (const float*)d_in[2];
    const float* b1  = (const float*)d_in[3];
    const float* W2  = (const float*)d_in[4];
    const float* s2  = (const float*)d_in[5];
    const float* b2  = (const float*)d_in[6];
    const float* W3  = (const float*)d_in[7];
    const float* s3  = (const float*)d_in[8];
    const float* b3  = (const float*)d_in[9];
    const float* W4  = (const float*)d_in[10];
    const float* s4  = (const float*)d_in[11];
    const float* b4  = (const float*)d_in[12];
    const float* W5  = (const float*)d_in[13];
    const float* s5  = (const float*)d_in[14];
    const float* b5  = (const float*)d_in[15];
    const float* L1w = (const float*)d_in[16];
    const float* s6  = (const float*)d_in[17];
    const float* b6  = (const float*)d_in[18];
    const float* L2w = (const float*)d_in[19];
    const float* L2b = (const float*)d_in[20];
    const float* s7  = (const float*)d_in[21];
    const float* b7  = (const float*)d_in[22];
    const float* L3w = (const float*)d_in[23];
    const float* L3b = (const float*)d_in[24];
    const float* F1w = (const float*)d_in[25];
    const float* s8  = (const float*)d_in[26];
    const float* b8  = (const float*)d_in[27];
    const float* F2w = (const float*)d_in[28];
    const float* F2b = (const float*)d_in[29];
    const float* s9  = (const float*)d_in[30];
    const float* b9  = (const float*)d_in[31];
    const float* F3w = (const float*)d_in[32];
    const float* F3b = (const float*)d_in[33];

    float* ws = (float*)d_ws;
    size_t off = 0;
    auto alloc = [&](size_t n) { float* p = ws + off; off += n; return p; };
    float* pts  = alloc((size_t)Bn * Np * 4);
    float* x1   = alloc((size_t)Bn * Np * 64);
    float* x2   = alloc((size_t)Bn * Np * 64);
    float* x3   = alloc((size_t)Bn * Np * 128);
    float* x4   = alloc((size_t)Bn * Np * 256);
    float* xcm  = alloc((size_t)Bn * Np * 128);   // aliased: pmax / psum
    float* xxb  = alloc((size_t)Bn * Np);
    int*   idxb = (int*)alloc((size_t)Bn * Np * Kn);
    float* g0   = alloc((size_t)Bn * 2048);
    float* g1   = alloc((size_t)Bn * 512);
    float* g2   = alloc((size_t)Bn * 256);
    float* y1   = alloc((size_t)Bn * 512);
    float* y2   = alloc((size_t)Bn * 256);
    float* WnsT2 = alloc(64 * 64);
    float* WdsT2 = alloc(64 * 64);
    float* WnsT3 = alloc(64 * 128);
    float* WdsT3 = alloc(64 * 128);
    float* WnsT4 = alloc(128 * 256);
    float* WdsT4 = alloc(128 * 256);
    ushortT* Bh2 = (ushortT*)alloc(64 * 64 / 2);
    ushortT* Bl2 = (ushortT*)alloc(64 * 64 / 2);
    ushortT* Bh3 = (ushortT*)alloc(64 * 128 / 2);
    ushortT* Bl3 = (ushortT*)alloc(64 * 128 / 2);
    ushortT* Bh4 = (ushortT*)alloc(128 * 256 / 2);
    ushortT* Bl4 = (ushortT*)alloc(128 * 256 / 2);
    ushortT* BhK = (ushortT*)alloc(1048576);   // knn B-frag hi (max C=128: 2M shorts)
    ushortT* BlK = (ushortT*)alloc(1048576);
    ushortT* Bh5 = (ushortT*)alloc(262144);    // W5 frag hi: 512K shorts
    ushortT* Bl5 = (ushortT*)alloc(262144);
    float* pmax = xcm;
    float* psum = xcm + 524288;
    float* cb2 = x2;
    float* cb3 = x3;
    float* cb4 = x4;

    // dynamic-LDS opt-ins (idempotent, safe pre-capture)
    auto shsz = [](int CP) { return 16 * CP * 2 * 2 + 64 + 16 * 1026 * 4; };
    int sh3 = shsz(40), sh64 = shsz(72), sh128 = shsz(136);
    int shw5 = 32 * 520 * 2 * 2;
    (void)hipFuncSetAttribute((const void*)k_knn6<3, 32, 4>, hipFuncAttributeMaxDynamicSharedMemorySize, sh3);
    (void)hipFuncSetAttribute((const void*)k_knn6<64, 64, 64>, hipFuncAttributeMaxDynamicSharedMemorySize, sh64);
    (void)hipFuncSetAttribute((const void*)k_knn6<128, 128, 128>, hipFuncAttributeMaxDynamicSharedMemorySize, sh128);
    (void)hipFuncSetAttribute((const void*)k_w5mfma, hipFuncAttributeMaxDynamicSharedMemorySize, shw5);

    k_transpose<<<Bn * Np / 256, 256, 0, stream>>>(x, pts);
    k_wsplit<<<16, 256, 0, stream>>>(W2, s2, 64, 64, WnsT2, WdsT2);
    k_wsplit<<<32, 256, 0, stream>>>(W3, s3, 64, 128, WnsT3, WdsT3);
    k_wsplit<<<128, 256, 0, stream>>>(W4, s4, 128, 256, WnsT4, WdsT4);
    k_wpack<<<16, 256, 0, stream>>>(W2, s2, 64, 64, Bh2, Bl2);
    k_wpack<<<32, 256, 0, stream>>>(W3, s3, 64, 128, Bh3, Bl3);
    k_wpack<<<128, 256, 0, stream>>>(W4, s4, 128, 256, Bh4, Bl4);
    k_w5pack<<<2048, 256, 0, stream>>>(W5, s5, Bh5, Bl5);

    // Layer 1: C=3
    k_xx<<<Bn * Np / 4, 256, 0, stream>>>(pts, xxb, 3, 4);
    k_bpack<3, 32, 4><<<2048, 256, 0, stream>>>(pts, BhK, BlK);
    k_knn6<3, 32, 4><<<Bn * Np / 16, 512, sh3, stream>>>(pts, BhK, BlK, xxb, idxb);
    k_edgeconv<3, 4, 64, 1, 8, 4><<<Bn * Np / 4, 256, 0, stream>>>(pts, idxb, W1, s1, b1, x1);

    // Layer 2: C=64 -> O=64
    k_xx<<<Bn * Np / 4, 256, 0, stream>>>(x1, xxb, 64, 64);
    k_bpack<64, 64, 64><<<4096, 256, 0, stream>>>(x1, BhK, BlK);
    k_knn6<64, 64, 64><<<Bn * Np / 16, 512, sh64, stream>>>(x1, BhK, BlK, xxb, idxb);
    k_ctr<64, 64, 4><<<Bn * Np / 32, 256, 0, stream>>>(x1, WdsT2, b2, cb2);
    k_ec3<64, 64, 2><<<Bn * Np / 2, 256, 0, stream>>>(x1, idxb, Bh2, Bl2, cb2, x2);

    // Layer 3: C=64 -> O=128
    k_xx<<<Bn * Np / 4, 256, 0, stream>>>(x2, xxb, 64, 64);
    k_bpack<64, 64, 64><<<4096, 256, 0, stream>>>(x2, BhK, BlK);
    k_knn6<64, 64, 64><<<Bn * Np / 16, 512, sh64, stream>>>(x2, BhK, BlK, xxb, idxb);
    k_ctr<64, 128, 8><<<Bn * Np / 32, 256, 0, stream>>>(x2, WdsT3, b3, cb3);
    k_ec3<64, 128, 2><<<Bn * Np / 2, 256, 0, stream>>>(x2, idxb, Bh3, Bl3, cb3, x3);

    // Layer 4: C=128 -> O=256
    k_xx<<<Bn * Np / 4, 256, 0, stream>>>(x3, xxb, 128, 128);
    k_bpack<128, 128, 128><<<8192, 256, 0, stream>>>(x3, BhK, BlK);
    k_knn6<128, 128, 128><<<Bn * Np / 16, 512, sh128, stream>>>(x3, BhK, BlK, xxb, idxb);
    k_ctr<128, 256, 8><<<Bn * Np / 32, 256, 0, stream>>>(x3, WdsT4, b4, cb4);
    k_ec3<128, 256, 2><<<Bn * Np / 2, 256, 0, stream>>>(x3, idxb, Bh4, Bl4, cb4, x4);

    // W5 + pooling (MFMA, 16-wave blocks)
    k_w5mfma<<<Bn * 64, 1024, shw5, stream>>>(x1, x2, x3, x4, Bh5, Bl5, b5, pmax, psum);
    k_poolred<<<Bn * 1024 / 256, 256, 0, stream>>>(pmax, psum, g0);

    float* out = (float*)d_out;
    k_fc<<<dim3(128, Bn), 256, 0, stream>>>(g0, 2048, 2048, L1w, nullptr, s6, b6, 1, g1, 512, 512);
    k_fc<<<dim3(64, Bn), 256, 0, stream>>>(g1, 512, 512, L2w, L2b, s7, b7, 1, g2, 256, 256);
    k_fc<<<dim3(2, Bn), 256, 0, stream>>>(g2, 256, 256, L3w, L3b, nullptr, nullptr, 0, out, 5, 5);
    k_fc<<<dim3(128, Bn), 256, 0, stream>>>(g0, 2048, 1024, F1w, nullptr, s8, b8, 1, y1, 512, 512);
    k_fc<<<dim3(64, Bn), 256, 0, stream>>>(y1, 512, 512, F2w, F2b, s9, b9, 1, y2, 256, 256);
    k_fc<<<dim3(2, Bn), 256, 0, stream>>>(y2, 256, 256, F3w, F3b, nullptr, nullptr, 0, out + 40, 5, 5);
}

// Round 16
// 900.228 us; speedup vs baseline: 1.0034x; 1.0034x over previous
//
#include <hip/hip_runtime.h>
#include <math.h>

constexpr int Bn = 8;
constexpr int Np = 2048;
constexpr int Kn = 32;
constexpr float NEGS = 0.2f;

typedef __attribute__((ext_vector_type(8))) short short8;
typedef __attribute__((ext_vector_type(4))) float f32x4;
typedef unsigned short ushortT;

__device__ __forceinline__ float lrelu(float v) { return v > 0.f ? v : NEGS * v; }

// DPP-based max step; ctrl/rmask as template args (builtin requires ICE operands)
template<int CTRL, int RMASK>
__device__ __forceinline__ float dppmax(float v) {
    int o = __float_as_int(v);
    int s = __builtin_amdgcn_update_dpp(o, o, CTRL, RMASK, 0xf, false);
    return fmaxf(v, __int_as_float(s));
}
// full 64-lane max via DPP (valid in lane 63), then readlane-broadcast
__device__ __forceinline__ float wave_max_dpp(float v) {
    v = dppmax<0x111, 0xf>(v);   // row_shr:1
    v = dppmax<0x112, 0xf>(v);   // row_shr:2
    v = dppmax<0x114, 0xf>(v);   // row_shr:4
    v = dppmax<0x118, 0xf>(v);   // row_shr:8
    v = dppmax<0x142, 0xa>(v);   // row_bcast:15 -> rows 1,3
    v = dppmax<0x143, 0xc>(v);   // row_bcast:31 -> row 3
    return __int_as_float(__builtin_amdgcn_readlane(__float_as_int(v), 63));
}

// split fp32 -> bf16 hi (truncate) + bf16 lo (residual, truncate); packed 2-at-a-time
__device__ __forceinline__ void cvt2u(float a, float b, unsigned& h, unsigned& l) {
    unsigned ua = __float_as_uint(a), ub = __float_as_uint(b);
    h = (ua >> 16) | (ub & 0xffff0000u);
    float ra = a - __uint_as_float(ua & 0xffff0000u);
    float rb = b - __uint_as_float(ub & 0xffff0000u);
    l = (__float_as_uint(ra) >> 16) | (__float_as_uint(rb) & 0xffff0000u);
}

// x [B,3,N] -> pts point-major [B*N, 4] (pad lane = 0)
__global__ __launch_bounds__(256) void k_transpose(const float* __restrict__ x, float* __restrict__ pts) {
    int i = blockIdx.x * 256 + threadIdx.x;
    int b = i / Np, n = i % Np;
    float p0 = x[((size_t)b * 3 + 0) * Np + n];
    float p1 = x[((size_t)b * 3 + 1) * Np + n];
    float p2 = x[((size_t)b * 3 + 2) * Np + n];
    float4 v = make_float4(p0, p1, p2, 0.f);
    *(float4*)&pts[(size_t)i * 4] = v;
}

// xx[i] = sum_c pm[i*ld+c]^2 ; one wave per point, 4 points per block
__global__ __launch_bounds__(256) void k_xx(const float* __restrict__ pm, float* __restrict__ xxg, int C, int ld) {
    int wid = threadIdx.x >> 6, lane = threadIdx.x & 63;
    int pt = blockIdx.x * 4 + wid;
    const float* row = pm + (size_t)pt * ld;
    float acc = 0.f;
    for (int c = lane; c < C; c += 64) { float v = row[c]; acc = fmaf(v, v, acc); }
    #pragma unroll
    for (int off = 32; off; off >>= 1) acc += __shfl_down(acc, off, 64);
    if (lane == 0) xxg[pt] = acc;
}

// Pack points into mfma_16x16x32 B-fragment order (bf16 hi/lo), per batch.
template<int C, int CK, int LD>
__global__ __launch_bounds__(256) void k_bpack(const float* __restrict__ Xpm,
                                               ushortT* __restrict__ Bh, ushortT* __restrict__ Bl) {
    constexpr int KS = CK / 32;
    int i = blockIdx.x * 256 + threadIdx.x;
    int j = i & 7;
    int lane = (i >> 3) & 63;
    int nt = (i >> 9) & 127;
    int rest = i >> 16;
    int ks = rest % KS;
    int b = rest / KS;
    int k = ks * 32 + (lane >> 4) * 8 + j;
    int n = nt * 16 + (lane & 15);
    float v = (k < C) ? Xpm[((size_t)b * Np + n) * LD + k] : 0.f;
    unsigned u = __float_as_uint(v);
    Bh[i] = (ushortT)(u >> 16);
    float r = v - __uint_as_float(u & 0xffff0000u);
    Bl[i] = (ushortT)(__float_as_uint(r) >> 16);
}

// MFMA kNN v8b: 512 threads / 8 waves; two rows per wave with interleaved extraction
// chains. __launch_bounds__(512,4) raises the VGPR cap to 128 (dynamic LDS hides the
// real occupancy from the backend, which otherwise caps at 64 VGPR and spills v0/v1).
template<int C, int CK, int LD>
__global__ __launch_bounds__(512, 4) void k_knn6(const float* __restrict__ Xpm,
                                                 const ushortT* __restrict__ Bh, const ushortT* __restrict__ Bl,
                                                 const float* __restrict__ xxg, int* __restrict__ idxo) {
    constexpr int KS = CK / 32, CP = CK + 8, CK4 = CK / 4, C4src = LD / 4;
    constexpr int SD = 1026;
    extern __shared__ char smem[];
    ushortT* Ah = (ushortT*)smem;              // [16][CP]
    ushortT* Al = Ah + 16 * CP;                // [16][CP]
    float* xxm = (float*)(Al + 16 * CP);       // [16]
    float* dl = xxm + 16;                      // [16][SD] distances (one column-half)
    int b = blockIdx.x / (Np / 16);
    int n0 = (blockIdx.x % (Np / 16)) * 16;
    int t = threadIdx.x;
    const float4* Xp4 = (const float4*)Xpm;
    for (int e = t; e < 16 * CK4; e += 512) {
        int r = e / CK4, c4 = e % CK4;
        float4 v = (c4 < C4src) ? Xp4[((size_t)b * Np + n0 + r) * C4src + c4] : make_float4(0.f, 0.f, 0.f, 0.f);
        unsigned h0, l0, h1, l1;
        cvt2u(v.x, v.y, h0, l0);
        cvt2u(v.z, v.w, h1, l1);
        *(uint2*)&Ah[r * CP + 4 * c4] = make_uint2(h0, h1);
        *(uint2*)&Al[r * CP + 4 * c4] = make_uint2(l0, l1);
    }
    if (t < 16) xxm[t] = xxg[b * Np + t + n0];
    __syncthreads();

    int w = t >> 6, lane = t & 63;
    int quad = lane >> 4, col = lane & 15;
    short8 ah[KS], al[KS];
    #pragma unroll
    for (int ks = 0; ks < KS; ++ks) {
        ah[ks] = *(const short8*)&Ah[col * CP + ks * 32 + quad * 8];
        al[ks] = *(const short8*)&Al[col * CP + ks * 32 + quad * 8];
    }
    float xmr[4];
    #pragma unroll
    for (int r = 0; r < 4; ++r) xmr[r] = xxm[quad * 4 + r];

    float v0[32], v1[32];
    #pragma unroll
    for (int cc = 0; cc < 2; ++cc) {
        // MFMA: 8 n-tiles per wave per chunk (2 at a time); chunk covers 64 tiles
        for (int i = 0; i < 4; ++i) {
            int ntl0 = w * 8 + 2 * i, ntl1 = ntl0 + 1;
            int ng0 = cc * 64 + ntl0, ng1 = cc * 64 + ntl1;
            f32x4 a0 = (f32x4){0.f, 0.f, 0.f, 0.f};
            f32x4 a1 = (f32x4){0.f, 0.f, 0.f, 0.f};
            #pragma unroll
            for (int ks = 0; ks < KS; ++ks) {
                int bi0 = (((b * KS + ks) * 128 + ng0) * 64 + lane) * 8;
                int bi1 = (((b * KS + ks) * 128 + ng1) * 64 + lane) * 8;
                short8 bh0 = *(const short8*)(Bh + bi0);
                short8 bl0 = *(const short8*)(Bl + bi0);
                short8 bh1 = *(const short8*)(Bh + bi1);
                short8 bl1 = *(const short8*)(Bl + bi1);
                a0 = __builtin_amdgcn_mfma_f32_16x16x32_bf16(ah[ks], bh0, a0, 0, 0, 0);
                a1 = __builtin_amdgcn_mfma_f32_16x16x32_bf16(ah[ks], bh1, a1, 0, 0, 0);
                a0 = __builtin_amdgcn_mfma_f32_16x16x32_bf16(ah[ks], bl0, a0, 0, 0, 0);
                a1 = __builtin_amdgcn_mfma_f32_16x16x32_bf16(ah[ks], bl1, a1, 0, 0, 0);
                a0 = __builtin_amdgcn_mfma_f32_16x16x32_bf16(al[ks], bh0, a0, 0, 0, 0);
                a1 = __builtin_amdgcn_mfma_f32_16x16x32_bf16(al[ks], bh1, a1, 0, 0, 0);
            }
            float xn0 = xxg[b * Np + ng0 * 16 + col];
            float xn1 = xxg[b * Np + ng1 * 16 + col];
            #pragma unroll
            for (int r = 0; r < 4; ++r) {
                int m = quad * 4 + r;
                dl[m * SD + ntl0 * 16 + col] = 2.f * a0[r] - xmr[r] - xn0;
                dl[m * SD + ntl1 * 16 + col] = 2.f * a1[r] - xmr[r] - xn1;
            }
        }
        __syncthreads();
        const float* dr0 = dl + (2 * w) * SD;
        const float* dr1 = dl + (2 * w + 1) * SD;
        #pragma unroll
        for (int j = 0; j < 16; ++j) {
            v0[cc * 16 + j] = dr0[lane + 64 * j];
            v1[cc * 16 + j] = dr1[lane + 64 * j];
        }
        __syncthreads();
    }

    // ---- selection: wave w owns rows 2w, 2w+1; two interleaved exact chains ----
    float g00, g01, g02, g03, g10, g11, g12, g13;
    int j00, j01, j02, j03, j10, j11, j12, j13;
    g00 = v0[0]; j00 = 0;
    g10 = v1[0]; j10 = 0;
    #pragma unroll
    for (int e = 1; e < 8; ++e) {
        if (v0[e] > g00) { g00 = v0[e]; j00 = e; }
        if (v1[e] > g10) { g10 = v1[e]; j10 = e; }
    }
    g01 = v0[8]; j01 = 8;
    g11 = v1[8]; j11 = 8;
    #pragma unroll
    for (int e = 1; e < 8; ++e) {
        if (v0[8 + e] > g01) { g01 = v0[8 + e]; j01 = 8 + e; }
        if (v1[8 + e] > g11) { g11 = v1[8 + e]; j11 = 8 + e; }
    }
    g02 = v0[16]; j02 = 16;
    g12 = v1[16]; j12 = 16;
    #pragma unroll
    for (int e = 1; e < 8; ++e) {
        if (v0[16 + e] > g02) { g02 = v0[16 + e]; j02 = 16 + e; }
        if (v1[16 + e] > g12) { g12 = v1[16 + e]; j12 = 16 + e; }
    }
    g03 = v0[24]; j03 = 24;
    g13 = v1[24]; j13 = 24;
    #pragma unroll
    for (int e = 1; e < 8; ++e) {
        if (v0[24 + e] > g03) { g03 = v0[24 + e]; j03 = 24 + e; }
        if (v1[24 + e] > g13) { g13 = v1[24 + e]; j13 = 24 + e; }
    }

    size_t ob0 = ((size_t)b * Np + n0 + 2 * w) * Kn;
    size_t ob1 = ((size_t)b * Np + n0 + 2 * w + 1) * Kn;
    for (int it = 0; it < Kn; ++it) {
        float lv0 = fmaxf(fmaxf(g00, g01), fmaxf(g02, g03));
        float lv1 = fmaxf(fmaxf(g10, g11), fmaxf(g12, g13));
        float Wv0 = wave_max_dpp(lv0);
        float Wv1 = wave_max_dpp(lv1);
        unsigned long long mk0 = __ballot(lv0 == Wv0);
        unsigned long long mk1 = __ballot(lv1 == Wv1);
        int own0 = __ffsll(mk0) - 1;
        int own1 = __ffsll(mk1) - 1;
        if (lane == own0) {
            int lj;
            if (g00 == Wv0) lj = j00;
            else if (g01 == Wv0) lj = j01;
            else if (g02 == Wv0) lj = j02;
            else lj = j03;
            idxo[ob0 + it] = lane + 64 * lj;
            int gg = lj >> 3;
            if (gg == 0) {
                #pragma unroll
                for (int e = 0; e < 8; ++e) if (e == lj) v0[e] = -INFINITY;
                g00 = v0[0]; j00 = 0;
                #pragma unroll
                for (int e = 1; e < 8; ++e) if (v0[e] > g00) { g00 = v0[e]; j00 = e; }
            } else if (gg == 1) {
                #pragma unroll
                for (int e = 0; e < 8; ++e) if (8 + e == lj) v0[8 + e] = -INFINITY;
                g01 = v0[8]; j01 = 8;
                #pragma unroll
                for (int e = 1; e < 8; ++e) if (v0[8 + e] > g01) { g01 = v0[8 + e]; j01 = 8 + e; }
            } else if (gg == 2) {
                #pragma unroll
                for (int e = 0; e < 8; ++e) if (16 + e == lj) v0[16 + e] = -INFINITY;
                g02 = v0[16]; j02 = 16;
                #pragma unroll
                for (int e = 1; e < 8; ++e) if (v0[16 + e] > g02) { g02 = v0[16 + e]; j02 = 16 + e; }
            } else {
                #pragma unroll
                for (int e = 0; e < 8; ++e) if (24 + e == lj) v0[24 + e] = -INFINITY;
                g03 = v0[24]; j03 = 24;
                #pragma unroll
                for (int e = 1; e < 8; ++e) if (v0[24 + e] > g03) { g03 = v0[24 + e]; j03 = 24 + e; }
            }
        }
        if (lane == own1) {
            int lj;
            if (g10 == Wv1) lj = j10;
            else if (g11 == Wv1) lj = j11;
            else if (g12 == Wv1) lj = j12;
            else lj = j13;
            idxo[ob1 + it] = lane + 64 * lj;
            int gg = lj >> 3;
            if (gg == 0) {
                #pragma unroll
                for (int e = 0; e < 8; ++e) if (e == lj) v1[e] = -INFINITY;
                g10 = v1[0]; j10 = 0;
                #pragma unroll
                for (int e = 1; e < 8; ++e) if (v1[e] > g10) { g10 = v1[e]; j10 = e; }
            } else if (gg == 1) {
                #pragma unroll
                for (int e = 0; e < 8; ++e) if (8 + e == lj) v1[8 + e] = -INFINITY;
                g11 = v1[8]; j11 = 8;
                #pragma unroll
                for (int e = 1; e < 8; ++e) if (v1[8 + e] > g11) { g11 = v1[8 + e]; j11 = 8 + e; }
            } else if (gg == 2) {
                #pragma unroll
                for (int e = 0; e < 8; ++e) if (16 + e == lj) v1[16 + e] = -INFINITY;
                g12 = v1[16]; j12 = 16;
                #pragma unroll
                for (int e = 1; e < 8; ++e) if (v1[16 + e] > g12) { g12 = v1[16 + e]; j12 = 16 + e; }
            } else {
                #pragma unroll
                for (int e = 0; e < 8; ++e) if (24 + e == lj) v1[24 + e] = -INFINITY;
                g13 = v1[24]; j13 = 24;
                #pragma unroll
                for (int e = 1; e < 8; ++e) if (v1[24 + e] > g13) { g13 = v1[24 + e]; j13 = 24 + e; }
            }
        }
    }
}

// W split+scale+transpose (fp32, for k_ctr): WdsT[c][o] = (W[o][C+c]-W[o][c])*s[o]
__global__ __launch_bounds__(256) void k_wsplit(const float* __restrict__ W, const float* __restrict__ s,
                                                int C, int O, float* __restrict__ WnsT, float* __restrict__ WdsT) {
    int i = blockIdx.x * 256 + threadIdx.x;
    if (i >= C * O) return;
    int c = i / O, o = i % O;
    float a = W[(size_t)o * 2 * C + c];
    float q = W[(size_t)o * 2 * C + C + c];
    float sv = s[o];
    WnsT[i] = a * sv;
    WdsT[i] = (q - a) * sv;
}

// Pack neighbor-half of W (scaled) into mfma_16x16x32 B-fragment order, split bf16 hi/lo.
__global__ __launch_bounds__(256) void k_wpack(const float* __restrict__ W, const float* __restrict__ s,
                                               int C, int O, ushortT* __restrict__ Bh, ushortT* __restrict__ Bl) {
    int i = blockIdx.x * 256 + threadIdx.x;
    if (i >= C * O) return;
    int k = i / O, o = i % O;
    float v = W[(size_t)o * 2 * C + k] * s[o];
    int ks = k >> 5, quad = (k >> 3) & 3, j = k & 7;
    int nt = o >> 4, lane = quad * 16 + (o & 15);
    int NT = O / 16;
    size_t idx = (((size_t)(ks * NT + nt)) * 64 + lane) * 8 + j;
    unsigned u = __float_as_uint(v);
    Bh[idx] = (ushortT)(u >> 16);
    float r = v - __uint_as_float(u & 0xffff0000u);
    Bl[idx] = (ushortT)(__float_as_uint(r) >> 16);
}

// Pack W5 (scaled by s5) [1024][512] into fragment order: KS=16, NT=64.
__global__ __launch_bounds__(256) void k_w5pack(const float* __restrict__ W5, const float* __restrict__ s5,
                                                ushortT* __restrict__ Bh, ushortT* __restrict__ Bl) {
    int i = blockIdx.x * 256 + threadIdx.x;   // 512*1024
    int k = i >> 10, o = i & 1023;
    float v = W5[(size_t)o * 512 + k] * s5[o];
    int ks = k >> 5, quad = (k >> 3) & 3, j = k & 7;
    int nt = o >> 4, lane = quad * 16 + (o & 15);
    size_t idx = (((size_t)(ks * 64 + nt)) * 64 + lane) * 8 + j;
    unsigned u = __float_as_uint(v);
    Bh[idx] = (ushortT)(u >> 16);
    float r = v - __uint_as_float(u & 0xffff0000u);
    Bl[idx] = (ushortT)(__float_as_uint(r) >> 16);
}

// cb[n][o] = sum_c ctr[n][c]*WdsT[c][o] + b[o].  32 points per block.
template<int C, int O, int OPT>
__global__ __launch_bounds__(256) void k_ctr(const float* __restrict__ Xpm, const float* __restrict__ WdsT,
                                             const float* __restrict__ bg, float* __restrict__ cb) {
    constexpr int OG = O / OPT, MG = 256 / OG, MPT = 32 / MG;
    constexpr int C4 = C / 4;
    __shared__ float xs[32][C];
    int b = blockIdx.x / (Np / 32);
    int n0 = (blockIdx.x % (Np / 32)) * 32;
    int t = threadIdx.x;
    const float4* Xp4 = (const float4*)Xpm;
    for (int e = t; e < 32 * C4; e += 256) {
        int pt = e / C4, c4 = e % C4;
        *(float4*)&xs[pt][4 * c4] = Xp4[((size_t)b * Np + n0 + pt) * C4 + c4];
    }
    __syncthreads();
    int og = t % OG, mg = t / OG;
    int o0 = og * OPT;
    float acc[MPT][OPT] = {};
    for (int c = 0; c < C; ++c) {
        float wv[OPT];
        #pragma unroll
        for (int p4 = 0; p4 < OPT / 4; ++p4)
            *(float4*)&wv[4 * p4] = *(const float4*)&WdsT[(size_t)c * O + o0 + 4 * p4];
        #pragma unroll
        for (int m = 0; m < MPT; ++m) {
            float xv = xs[mg * MPT + m][c];
            #pragma unroll
            for (int p = 0; p < OPT; ++p) acc[m][p] = fmaf(wv[p], xv, acc[m][p]);
        }
    }
    #pragma unroll
    for (int m = 0; m < MPT; ++m) {
        #pragma unroll
        for (int p = 0; p < OPT; ++p) {
            int o = o0 + p;
            cb[((size_t)b * Np + n0 + mg * MPT + m) * O + o] = acc[m][p] + bg[o];
        }
    }
}

// MFMA EdgeConv GEMM v2 (split-bf16): waves split the O dimension.
template<int C, int O, int PTS>
__global__ __launch_bounds__(256, 4) void k_ec3(const float* __restrict__ Xpm, const int* __restrict__ idxg,
                                                const ushortT* __restrict__ Bh, const ushortT* __restrict__ Bl,
                                                const float* __restrict__ cb,
                                                float* __restrict__ Ypm) {
    static_assert(PTS == 2, "M=64 mapping");
    constexpr int M = 64, NT = O / 16, NT4 = NT / 4, KS = C / 32, C4 = C / 4, CP = C + 8;
    static_assert(NT4 >= 1, "O>=64");
    __shared__ ushortT Ah[M][CP];
    __shared__ ushortT Al[M][CP];
    int b = blockIdx.x / (Np / PTS);
    int n0 = (blockIdx.x % (Np / PTS)) * PTS;
    int t = threadIdx.x;
    const int* ip = idxg + ((size_t)b * Np + n0) * Kn;
    const float4* Xp4 = (const float4*)Xpm;
    for (int e = t; e < M * C4; e += 256) {
        int row = e / C4, c4 = e % C4;
        float4 v = Xp4[((size_t)b * Np + ip[row]) * C4 + c4];
        unsigned h0, l0, h1, l1;
        cvt2u(v.x, v.y, h0, l0);
        cvt2u(v.z, v.w, h1, l1);
        *(uint2*)&Ah[row][4 * c4] = make_uint2(h0, h1);
        *(uint2*)&Al[row][4 * c4] = make_uint2(l0, l1);
    }
    __syncthreads();
    int w = t >> 6, lane = t & 63;
    int quad = lane >> 4, col = lane & 15;
    f32x4 acc[4][NT4];
    #pragma unroll
    for (int mt = 0; mt < 4; ++mt)
        #pragma unroll
        for (int i = 0; i < NT4; ++i) acc[mt][i] = (f32x4){0.f, 0.f, 0.f, 0.f};
    for (int ks = 0; ks < KS; ++ks) {
        int kb = ks * 32 + quad * 8;
        short8 ah[4], al[4];
        #pragma unroll
        for (int mt = 0; mt < 4; ++mt) {
            ah[mt] = *(const short8*)&Ah[mt * 16 + col][kb];
            al[mt] = *(const short8*)&Al[mt * 16 + col][kb];
        }
        #pragma unroll
        for (int i = 0; i < NT4; ++i) {
            int nt = w * NT4 + i;
            size_t bi = (((size_t)(ks * NT + nt)) * 64 + lane) * 8;
            short8 bh = *(const short8*)(Bh + bi);
            short8 bl = *(const short8*)(Bl + bi);
            #pragma unroll
            for (int mt = 0; mt < 4; ++mt) {
                acc[mt][i] = __builtin_amdgcn_mfma_f32_16x16x32_bf16(ah[mt], bh, acc[mt][i], 0, 0, 0);
                acc[mt][i] = __builtin_amdgcn_mfma_f32_16x16x32_bf16(ah[mt], bl, acc[mt][i], 0, 0, 0);
                acc[mt][i] = __builtin_amdgcn_mfma_f32_16x16x32_bf16(al[mt], bh, acc[mt][i], 0, 0, 0);
            }
        }
    }
    #pragma unroll
    for (int pt = 0; pt < PTS; ++pt) {
        size_t ni = (size_t)b * Np + n0 + pt;
        #pragma unroll
        for (int i = 0; i < NT4; ++i) {
            f32x4 a0 = acc[2 * pt][i], a1 = acc[2 * pt + 1][i];
            float m = fmaxf(fmaxf(fmaxf(a0[0], a0[1]), fmaxf(a0[2], a0[3])),
                            fmaxf(fmaxf(a1[0], a1[1]), fmaxf(a1[2], a1[3])));
            m = fmaxf(m, __shfl_xor(m, 16, 64));
            m = fmaxf(m, __shfl_xor(m, 32, 64));
            if (lane < 16) {
                int o = (w * NT4 + i) * 16 + col;
                Ypm[ni * O + o] = lrelu(m + cb[ni * O + o]);
            }
        }
    }
}

// Legacy fused EdgeConv for layer 1 (C=3)
template<int C, int CPAD, int O, int OPT, int KPT, int PTS>
__global__ __launch_bounds__(256) void k_edgeconv(
    const float* __restrict__ Xpm, const int* __restrict__ idxg,
    const float* __restrict__ W, const float* __restrict__ sg, const float* __restrict__ bg,
    float* __restrict__ Ypm)
{
    constexpr int OG = O / OPT;
    constexpr int NKG = 256 / OG;
    constexpr int CL = CPAD + 4;
    static_assert(NKG * KPT == Kn, "k mapping");
    __shared__ float nbr[PTS][Kn][CL];
    __shared__ float ctr[PTS][CPAD];
    __shared__ float red[PTS][OPT][4][OG];
    int blk = blockIdx.x;
    int b = blk / (Np / PTS);
    int n0 = (blk % (Np / PTS)) * PTS;
    int t = threadIdx.x;
    int lane = t & 63, wid = t >> 6;
    const int* ip = idxg + ((size_t)b * Np + n0) * Kn;
    const float4* Xp4 = (const float4*)Xpm;
    constexpr int C4 = CPAD / 4;
    for (int e = t; e < PTS * C4; e += 256) {
        int pt = e / C4, c4 = e % C4;
        *(float4*)&ctr[pt][4 * c4] = Xp4[((size_t)b * Np + n0 + pt) * C4 + c4];
    }
    for (int e = t; e < PTS * Kn * C4; e += 256) {
        int pt = e / (Kn * C4);
        int r = e % (Kn * C4);
        int k = r / C4, c4 = r % C4;
        int nb = ip[pt * Kn + k];
        *(float4*)&nbr[pt][k][4 * c4] = Xp4[((size_t)b * Np + nb) * C4 + c4];
    }
    __syncthreads();
    int og = t % OG, kg = t / OG;
    float acc[PTS][OPT][KPT] = {};
    float ctt[PTS][OPT] = {};
    for (int c0 = 0; c0 < CPAD; c0 += 4) {
        float wn[OPT][4], wd[OPT][4];
        #pragma unroll
        for (int p = 0; p < OPT; ++p) {
            #pragma unroll
            for (int cc = 0; cc < 4; ++cc) {
                int c = c0 + cc;
                float a = (c < C) ? W[(size_t)(og + p * OG) * (2 * C) + c] : 0.f;
                float q = (c < C) ? W[(size_t)(og + p * OG) * (2 * C) + C + c] : 0.f;
                wn[p][cc] = a; wd[p][cc] = q - a;
            }
        }
        #pragma unroll
        for (int pt = 0; pt < PTS; ++pt) {
            float4 cv = *(const float4*)&ctr[pt][c0];
            #pragma unroll
            for (int p = 0; p < OPT; ++p) {
                ctt[pt][p] = fmaf(wd[p][0], cv.x, ctt[pt][p]);
                ctt[pt][p] = fmaf(wd[p][1], cv.y, ctt[pt][p]);
                ctt[pt][p] = fmaf(wd[p][2], cv.z, ctt[pt][p]);
                ctt[pt][p] = fmaf(wd[p][3], cv.w, ctt[pt][p]);
            }
        }
        #pragma unroll
        for (int pt = 0; pt < PTS; ++pt) {
            #pragma unroll
            for (int k = 0; k < KPT; ++k) {
                float4 nv = *(const float4*)&nbr[pt][kg * KPT + k][c0];
                #pragma unroll
                for (int p = 0; p < OPT; ++p) {
                    acc[pt][p][k] = fmaf(wn[p][0], nv.x, acc[pt][p][k]);
                    acc[pt][p][k] = fmaf(wn[p][1], nv.y, acc[pt][p][k]);
                    acc[pt][p][k] = fmaf(wn[p][2], nv.z, acc[pt][p][k]);
                    acc[pt][p][k] = fmaf(wn[p][3], nv.w, acc[pt][p][k]);
                }
            }
        }
    }
    #pragma unroll
    for (int pt = 0; pt < PTS; ++pt) {
        #pragma unroll
        for (int p = 0; p < OPT; ++p) {
            int o = og + p * OG;
            float sv = sg[o], bv = bg[o];
            float m = -INFINITY;
            #pragma unroll
            for (int k = 0; k < KPT; ++k) {
                float hv = fmaf(acc[pt][p][k] + ctt[pt][p], sv, bv);
                m = fmaxf(m, lrelu(hv));
            }
            #pragma unroll
            for (int s = OG; s < 64; s <<= 1) m = fmaxf(m, __shfl_xor(m, s, 64));
            if (lane < OG) red[pt][p][wid][lane] = m;
        }
    }
    __syncthreads();
    if (t < OG) {
        #pragma unroll
        for (int pt = 0; pt < PTS; ++pt) {
            #pragma unroll
            for (int p = 0; p < OPT; ++p) {
                float m = fmaxf(fmaxf(red[pt][p][0][t], red[pt][p][1][t]),
                                fmaxf(red[pt][p][2][t], red[pt][p][3][t]));
                int o = t + p * OG;
                Ypm[((size_t)b * Np + n0 + pt) * O + o] = m;
            }
        }
    }
}

// MFMA W5 (K=512, O=1024) + bias + LeakyReLU + max/sum pool over 32 points -> partials.
__global__ __launch_bounds__(1024, 4) void k_w5mfma(
    const float* __restrict__ x1, const float* __restrict__ x2,
    const float* __restrict__ x3, const float* __restrict__ x4,
    const ushortT* __restrict__ Bh, const ushortT* __restrict__ Bl,
    const float* __restrict__ b5,
    float* __restrict__ pmax, float* __restrict__ psum)
{
    constexpr int CP = 520;                 // 512 + 8 pad
    extern __shared__ char smem[];
    ushortT* Ah = (ushortT*)smem;           // [32][CP]
    ushortT* Al = Ah + 32 * CP;             // [32][CP]
    int b = blockIdx.x >> 6;
    int chunk = blockIdx.x & 63;
    int n0 = chunk * 32;
    int t = threadIdx.x;
    for (int e = t; e < 32 * 128; e += 1024) {
        int pt = e >> 7, c4 = e & 127;
        size_t pi = (size_t)b * Np + n0 + pt;
        float4 v;
        if (c4 < 16)      v = ((const float4*)x1)[pi * 16 + c4];
        else if (c4 < 32) v = ((const float4*)x2)[pi * 16 + (c4 - 16)];
        else if (c4 < 64) v = ((const float4*)x3)[pi * 32 + (c4 - 32)];
        else              v = ((const float4*)x4)[pi * 64 + (c4 - 64)];
        unsigned h0, l0, h1, l1;
        cvt2u(v.x, v.y, h0, l0);
        cvt2u(v.z, v.w, h1, l1);
        *(uint2*)&Ah[pt * CP + 4 * c4] = make_uint2(h0, h1);
        *(uint2*)&Al[pt * CP + 4 * c4] = make_uint2(l0, l1);
    }
    __syncthreads();
    int w = t >> 6, lane = t & 63;
    int quad = lane >> 4, col = lane & 15;
    size_t pb = ((size_t)(b * 64 + chunk)) * 1024;
    for (int oi = 0; oi < 4; ++oi) {
        int nt = w * 4 + oi;
        f32x4 a0 = (f32x4){0.f, 0.f, 0.f, 0.f};
        f32x4 a1 = (f32x4){0.f, 0.f, 0.f, 0.f};
        #pragma unroll 2
        for (int ks = 0; ks < 16; ++ks) {
            size_t bi = (((size_t)(ks * 64 + nt)) * 64 + lane) * 8;
            short8 bh = *(const short8*)(Bh + bi);
            short8 bl = *(const short8*)(Bl + bi);
            int ao = ks * 32 + quad * 8;
            short8 ah0 = *(const short8*)&Ah[col * CP + ao];
            short8 al0 = *(const short8*)&Al[col * CP + ao];
            short8 ah1 = *(const short8*)&Ah[(16 + col) * CP + ao];
            short8 al1 = *(const short8*)&Al[(16 + col) * CP + ao];
            a0 = __builtin_amdgcn_mfma_f32_16x16x32_bf16(ah0, bh, a0, 0, 0, 0);
            a1 = __builtin_amdgcn_mfma_f32_16x16x32_bf16(ah1, bh, a1, 0, 0, 0);
            a0 = __builtin_amdgcn_mfma_f32_16x16x32_bf16(ah0, bl, a0, 0, 0, 0);
            a1 = __builtin_amdgcn_mfma_f32_16x16x32_bf16(ah1, bl, a1, 0, 0, 0);
            a0 = __builtin_amdgcn_mfma_f32_16x16x32_bf16(al0, bh, a0, 0, 0, 0);
            a1 = __builtin_amdgcn_mfma_f32_16x16x32_bf16(al1, bh, a1, 0, 0, 0);
        }
        float bb = b5[nt * 16 + col];
        float mx = -INFINITY, sm = 0.f;
        #pragma unroll
        for (int r = 0; r < 4; ++r) {
            float v0 = lrelu(a0[r] + bb);
            float v1 = lrelu(a1[r] + bb);
            mx = fmaxf(mx, fmaxf(v0, v1));
            sm += v0 + v1;
        }
        mx = fmaxf(mx, __shfl_xor(mx, 16, 64));
        mx = fmaxf(mx, __shfl_xor(mx, 32, 64));
        sm += __shfl_xor(sm, 16, 64);
        sm += __shfl_xor(sm, 32, 64);
        if (lane < 16) {
            pmax[pb + nt * 16 + col] = mx;
            psum[pb + nt * 16 + col] = sm;
        }
    }
}

__global__ __launch_bounds__(256) void k_poolred(const float* __restrict__ pmax, const float* __restrict__ psum,
                                                 float* __restrict__ g0) {
    int i = blockIdx.x * 256 + threadIdx.x;
    int b = i >> 10, o = i & 1023;
    float mx = -INFINITY, sm = 0.f;
    for (int ch = 0; ch < 64; ++ch) {
        size_t idx = ((size_t)(b * 64 + ch)) * 1024 + o;
        mx = fmaxf(mx, pmax[idx]);
        sm += psum[idx];
    }
    g0[(size_t)b * 2048 + o] = mx;
    g0[(size_t)b * 2048 + 1024 + o] = sm * (1.f / Np);
}

__global__ __launch_bounds__(256) void k_fc(const float* __restrict__ In, int ldIn, int C,
                                            const float* __restrict__ Wm,
                                            const float* __restrict__ bias,
                                            const float* __restrict__ sc, const float* __restrict__ bnb,
                                            int leaky, float* __restrict__ Out, int ldOut, int O) {
    int wid = threadIdx.x >> 6, lane = threadIdx.x & 63;
    int o = blockIdx.x * 4 + wid;
    int b = blockIdx.y;
    if (o >= O) return;
    const float* in = In + (size_t)b * ldIn;
    const float* wr = Wm + (size_t)o * C;
    float acc = 0.f;
    for (int c = lane; c < C; c += 64) acc = fmaf(in[c], wr[c], acc);
    #pragma unroll
    for (int off = 32; off; off >>= 1) acc += __shfl_down(acc, off, 64);
    if (lane == 0) {
        float v = acc + (bias ? bias[o] : 0.f);
        if (sc) v = fmaf(v, sc[o], bnb[o]);
        if (leaky) v = lrelu(v);
        Out[(size_t)b * ldOut + o] = v;
    }
}

extern "C" void kernel_launch(void* const* d_in, const int* in_sizes, int n_in,
                              void* d_out, int out_size, void* d_ws, size_t ws_size,
                              hipStream_t stream) {
    const float* x   = (const float*)d_in[0];
    const float* W1  = (const float*)d_in[1];
    const float* s1  = (const float*)d_in[2];
    const float* b1  = (const float*)d_in[3];
    const float* W2  = (const float*)d_in[4];
    const float* s2  = (const float*)d_in[5];
    const float* b2  = (const float*)d_in[6];
    const float* W3  = (const float*)d_in[7];
    const float* s3  = (const float*)d_in[8];
    const float* b3  = (const float*)d_in[9];
    const float* W4  = (const float*)d_in[10];
    const float* s4  = (const float*)d_in[11];
    const float* b4  = (const float*)d_in[12];
    const float* W5  = (const float*)d_in[13];
    const float* s5  = (const float*)d_in[14];
    const float* b5  = (const float*)d_in[15];
    const float* L1w = (const float*)d_in[16];
    const float* s6  = (const float*)d_in[17];
    const float* b6  = (const float*)d_in[18];
    const float* L2w = (const float*)d_in[19];
    const float* L2b = (const float*)d_in[20];
    const float* s7  = (const float*)d_in[21];
    const float* b7  = (const float*)d_in[22];
    const float* L3w = (const float*)d_in[23];
    const float* L3b = (const float*)d_in[24];
    const float* F1w = (const float*)d_in[25];
    const float* s8  = (const float*)d_in[26];
    const float* b8  = (const float*)d_in[27];
    const float* F2w = (const float*)d_in[28];
    const float* F2b = (const float*)d_in[29];
    const float* s9  = (const float*)d_in[30];
    const float* b9  = (const float*)d_in[31];
    const float* F3w = (const float*)d_in[32];
    const float* F3b = (const float*)d_in[33];

    float* ws = (float*)d_ws;
    size_t off = 0;
    auto alloc = [&](size_t n) { float* p = ws + off; off += n; return p; };
    float* pts  = alloc((size_t)Bn * Np * 4);
    float* x1   = alloc((size_t)Bn * Np * 64);
    float* x2   = alloc((size_t)Bn * Np * 64);
    float* x3   = alloc((size_t)Bn * Np * 128);
    float* x4   = alloc((size_t)Bn * Np * 256);
    float* xcm  = alloc((size_t)Bn * Np * 128);   // aliased: pmax / psum
    float* xxb  = alloc((size_t)Bn * Np);
    int*   idxb = (int*)alloc((size_t)Bn * Np * Kn);
    float* g0   = alloc((size_t)Bn * 2048);
    float* g1   = alloc((size_t)Bn * 512);
    float* g2   = alloc((size_t)Bn * 256);
    float* y1   = alloc((size_t)Bn * 512);
    float* y2   = alloc((size_t)Bn * 256);
    float* WnsT2 = alloc(64 * 64);
    float* WdsT2 = alloc(64 * 64);
    float* WnsT3 = alloc(64 * 128);
    float* WdsT3 = alloc(64 * 128);
    float* WnsT4 = alloc(128 * 256);
    float* WdsT4 = alloc(128 * 256);
    ushortT* Bh2 = (ushortT*)alloc(64 * 64 / 2);
    ushortT* Bl2 = (ushortT*)alloc(64 * 64 / 2);
    ushortT* Bh3 = (ushortT*)alloc(64 * 128 / 2);
    ushortT* Bl3 = (ushortT*)alloc(64 * 128 / 2);
    ushortT* Bh4 = (ushortT*)alloc(128 * 256 / 2);
    ushortT* Bl4 = (ushortT*)alloc(128 * 256 / 2);
    ushortT* BhK = (ushortT*)alloc(1048576);   // knn B-frag hi (max C=128: 2M shorts)
    ushortT* BlK = (ushortT*)alloc(1048576);
    ushortT* Bh5 = (ushortT*)alloc(262144);    // W5 frag hi: 512K shorts
    ushortT* Bl5 = (ushortT*)alloc(262144);
    float* pmax = xcm;
    float* psum = xcm + 524288;
    float* cb2 = x2;
    float* cb3 = x3;
    float* cb4 = x4;

    // dynamic-LDS opt-ins (idempotent, safe pre-capture)
    auto shsz = [](int CP) { return 16 * CP * 2 * 2 + 64 + 16 * 1026 * 4; };
    int sh3 = shsz(40), sh64 = shsz(72), sh128 = shsz(136);
    int shw5 = 32 * 520 * 2 * 2;
    (void)hipFuncSetAttribute((const void*)k_knn6<3, 32, 4>, hipFuncAttributeMaxDynamicSharedMemorySize, sh3);
    (void)hipFuncSetAttribute((const void*)k_knn6<64, 64, 64>, hipFuncAttributeMaxDynamicSharedMemorySize, sh64);
    (void)hipFuncSetAttribute((const void*)k_knn6<128, 128, 128>, hipFuncAttributeMaxDynamicSharedMemorySize, sh128);
    (void)hipFuncSetAttribute((const void*)k_w5mfma, hipFuncAttributeMaxDynamicSharedMemorySize, shw5);

    k_transpose<<<Bn * Np / 256, 256, 0, stream>>>(x, pts);
    k_wsplit<<<16, 256, 0, stream>>>(W2, s2, 64, 64, WnsT2, WdsT2);
    k_wsplit<<<32, 256, 0, stream>>>(W3, s3, 64, 128, WnsT3, WdsT3);
    k_wsplit<<<128, 256, 0, stream>>>(W4, s4, 128, 256, WnsT4, WdsT4);
    k_wpack<<<16, 256, 0, stream>>>(W2, s2, 64, 64, Bh2, Bl2);
    k_wpack<<<32, 256, 0, stream>>>(W3, s3, 64, 128, Bh3, Bl3);
    k_wpack<<<128, 256, 0, stream>>>(W4, s4, 128, 256, Bh4, Bl4);
    k_w5pack<<<2048, 256, 0, stream>>>(W5, s5, Bh5, Bl5);

    // Layer 1: C=3
    k_xx<<<Bn * Np / 4, 256, 0, stream>>>(pts, xxb, 3, 4);
    k_bpack<3, 32, 4><<<2048, 256, 0, stream>>>(pts, BhK, BlK);
    k_knn6<3, 32, 4><<<Bn * Np / 16, 512, sh3, stream>>>(pts, BhK, BlK, xxb, idxb);
    k_edgeconv<3, 4, 64, 1, 8, 4><<<Bn * Np / 4, 256, 0, stream>>>(pts, idxb, W1, s1, b1, x1);

    // Layer 2: C=64 -> O=64
    k_xx<<<Bn * Np / 4, 256, 0, stream>>>(x1, xxb, 64, 64);
    k_bpack<64, 64, 64><<<4096, 256, 0, stream>>>(x1, BhK, BlK);
    k_knn6<64, 64, 64><<<Bn * Np / 16, 512, sh64, stream>>>(x1, BhK, BlK, xxb, idxb);
    k_ctr<64, 64, 4><<<Bn * Np / 32, 256, 0, stream>>>(x1, WdsT2, b2, cb2);
    k_ec3<64, 64, 2><<<Bn * Np / 2, 256, 0, stream>>>(x1, idxb, Bh2, Bl2, cb2, x2);

    // Layer 3: C=64 -> O=128
    k_xx<<<Bn * Np / 4, 256, 0, stream>>>(x2, xxb, 64, 64);
    k_bpack<64, 64, 64><<<4096, 256, 0, stream>>>(x2, BhK, BlK);
    k_knn6<64, 64, 64><<<Bn * Np / 16, 512, sh64, stream>>>(x2, BhK, BlK, xxb, idxb);
    k_ctr<64, 128, 8><<<Bn * Np / 32, 256, 0, stream>>>(x2, WdsT3, b3, cb3);
    k_ec3<64, 128, 2><<<Bn * Np / 2, 256, 0, stream>>>(x2, idxb, Bh3, Bl3, cb3, x3);

    // Layer 4: C=128 -> O=256
    k_xx<<<Bn * Np / 4, 256, 0, stream>>>(x3, xxb, 128, 128);
    k_bpack<128, 128, 128><<<8192, 256, 0, stream>>>(x3, BhK, BlK);
    k_knn6<128, 128, 128><<<Bn * Np / 16, 512, sh128, stream>>>(x3, BhK, BlK, xxb, idxb);
    k_ctr<128, 256, 8><<<Bn * Np / 32, 256, 0, stream>>>(x3, WdsT4, b4, cb4);
    k_ec3<128, 256, 2><<<Bn * Np / 2, 256, 0, stream>>>(x3, idxb, Bh4, Bl4, cb4, x4);

    // W5 + pooling (MFMA, 16-wave blocks)
    k_w5mfma<<<Bn * 64, 1024, shw5, stream>>>(x1, x2, x3, x4, Bh5, Bl5, b5, pmax, psum);
    k_poolred<<<Bn * 1024 / 256, 256, 0, stream>>>(pmax, psum, g0);

    float* out = (float*)d_out;
    k_fc<<<dim3(128, Bn), 256, 0, stream>>>(g0, 2048, 2048, L1w, nullptr, s6, b6, 1, g1, 512, 512);
    k_fc<<<dim3(64, Bn), 256, 0, stream>>>(g1, 512, 512, L2w, L2b, s7, b7, 1, g2, 256, 256);
    k_fc<<<dim3(2, Bn), 256, 0, stream>>>(g2, 256, 256, L3w, L3b, nullptr, nullptr, 0, out, 5, 5);
    k_fc<<<dim3(128, Bn), 256, 0, stream>>>(g0, 2048, 1024, F1w, nullptr, s8, b8, 1, y1, 512, 512);
    k_fc<<<dim3(64, Bn), 256, 0, stream>>>(y1, 512, 512, F2w, F2b, s9, b9, 1, y2, 256, 256);
    k_fc<<<dim3(2, Bn), 256, 0, stream>>>(y2, 256, 256, F3w, F3b, nullptr, nullptr, 0, out + 40, 5, 5);
}